// Round 6
// baseline (239.362 us; speedup 1.0000x reference)
//
#include <hip/hip_runtime.h>
#include <hip/hip_bf16.h>
#include <stdint.h>

#define T_TOK 4096
#define DH 1024
#define DI 1408
#define NE 8
#define TOPK 2
#define PADROWS 10240   // 8192 assignments + up to 8*255 pad (256-row tiles)

typedef short s16x8 __attribute__((ext_vector_type(8)));
typedef float f32x4 __attribute__((ext_vector_type(4)));

__device__ inline unsigned f2bf(float f) {
    __hip_bfloat16 h = __float2bfloat16(f);
    return (unsigned)*(unsigned short*)&h;
}

#define GLDS(src, dst) __builtin_amdgcn_global_load_lds( \
    (const __attribute__((address_space(1))) void*)(src), \
    (__attribute__((address_space(3))) void*)(dst), 16, 0, 0)

// ---------------- fp32 -> bf16 bulk convert (3 weight tensors, one launch) ----------------
__global__ __launch_bounds__(256) void cvt3_kernel(const float* __restrict__ s0,
        const float* __restrict__ s1, const float* __restrict__ s2,
        unsigned short* __restrict__ t0, unsigned short* __restrict__ t1,
        unsigned short* __restrict__ t2, int n4) {
    const float* src = blockIdx.y == 0 ? s0 : (blockIdx.y == 1 ? s1 : s2);
    unsigned short* dst = blockIdx.y == 0 ? t0 : (blockIdx.y == 1 ? t1 : t2);
    int i = blockIdx.x * blockDim.x + threadIdx.x;
    int stride = gridDim.x * blockDim.x;
    for (; i < n4; i += stride) {
        float4 v = ((const float4*)src)[i];
        uint2 o;
        o.x = f2bf(v.x) | (f2bf(v.y) << 16);
        o.y = f2bf(v.z) | (f2bf(v.w) << 16);
        ((uint2*)dst)[i] = o;
    }
}

// ---------------- router: logits, softmax, top-2, renorm; x->bf16. NO atomics ----------------
__global__ __launch_bounds__(256) void router_kernel(const float* __restrict__ x,
                              const float* __restrict__ gw,
                              float* __restrict__ logits_out,
                              int* __restrict__ tokE, float* __restrict__ tokW,
                              unsigned short* __restrict__ xb) {
    int wave = threadIdx.x >> 6;
    int lane = threadIdx.x & 63;
    int t = blockIdx.x * 4 + wave;
    const float4* xr = (const float4*)(x + (size_t)t * DH);

    float acc[NE];
#pragma unroll
    for (int e = 0; e < NE; ++e) acc[e] = 0.f;

#pragma unroll
    for (int i = 0; i < 4; ++i) {
        float4 xv = xr[lane + i * 64];
#pragma unroll
        for (int e = 0; e < NE; ++e) {
            float4 g = ((const float4*)(gw + (size_t)e * DH))[lane + i * 64];
            acc[e] += xv.x * g.x + xv.y * g.y + xv.z * g.z + xv.w * g.w;
        }
        uint2 o;
        o.x = f2bf(xv.x) | (f2bf(xv.y) << 16);
        o.y = f2bf(xv.z) | (f2bf(xv.w) << 16);
        *(uint2*)(xb + (size_t)t * DH + (lane + i * 64) * 4) = o;
    }
#pragma unroll
    for (int e = 0; e < NE; ++e) {
#pragma unroll
        for (int off = 32; off > 0; off >>= 1) acc[e] += __shfl_xor(acc[e], off, 64);
    }
    if (lane == 0) {
        float mx = acc[0];
#pragma unroll
        for (int e = 1; e < NE; ++e) mx = fmaxf(mx, acc[e]);
        float p[NE]; float s = 0.f;
#pragma unroll
        for (int e = 0; e < NE; ++e) { p[e] = expf(acc[e] - mx); s += p[e]; }
        float inv = 1.f / s;
#pragma unroll
        for (int e = 0; e < NE; ++e) p[e] *= inv;
        int i0 = 0, i1 = -1; float p0 = -1.f, p1 = -1.f;
#pragma unroll
        for (int e = 0; e < NE; ++e) {
            float v = p[e];
            if (v > p0) { p1 = p0; i1 = i0; p0 = v; i0 = e; }
            else if (v > p1) { p1 = v; i1 = e; }
        }
        float wsum = p0 + p1;
#pragma unroll
        for (int e = 0; e < NE; ++e) logits_out[(size_t)t * NE + e] = acc[e];
        tokE[2 * t]     = i0;  tokE[2 * t + 1] = i1;
        tokW[2 * t]     = p0 / wsum;  tokW[2 * t + 1] = p1 / wsum;
    }
}

// ---------------- histogram + prefix (pad 256): single block, ballot popcounts ----------------
__global__ __launch_bounds__(256) void hist_kernel(const int* __restrict__ tokE,
        int* __restrict__ counts, int* __restrict__ padOff) {
    __shared__ int wc[4][NE];
    int tid = threadIdx.x;
    int wave = tid >> 6, lane = tid & 63;
    int cnt[NE];
#pragma unroll
    for (int e = 0; e < NE; ++e) cnt[e] = 0;
    for (int i = tid; i < T_TOK * TOPK; i += 256) {
        int v = tokE[i];
#pragma unroll
        for (int e = 0; e < NE; ++e)
            cnt[e] += (int)__popcll(__ballot(v == e));
    }
    if (lane == 0) {
#pragma unroll
        for (int e = 0; e < NE; ++e) wc[wave][e] = cnt[e];
    }
    __syncthreads();
    if (tid == 0) {
        int r = 0;
        for (int e = 0; e < NE; ++e) {
            int c = wc[0][e] + wc[1][e] + wc[2][e] + wc[3][e];
            counts[e] = c;
            padOff[e] = r;
            r += ((c + 255) >> 8) << 8;
        }
        padOff[NE] = r;
    }
}

// ---------------- scatter: wave-aggregated cursor atomics ----------------
__global__ __launch_bounds__(256) void scatter_kernel(const int* __restrict__ tokE,
                               const int* __restrict__ padOff, int* __restrict__ cursor,
                               int* __restrict__ assignTok, int* __restrict__ tokSlot) {
    int t = blockIdx.x * blockDim.x + threadIdx.x;
    int lane = threadIdx.x & 63;
    unsigned long long lmask = (1ull << lane) - 1ull;
#pragma unroll
    for (int k = 0; k < TOPK; ++k) {
        int e = tokE[2 * t + k];
#pragma unroll
        for (int ex = 0; ex < NE; ++ex) {
            unsigned long long m = __ballot(e == ex);
            if (e == ex) {
                int rank = (int)__popcll(m & lmask);
                int leader = __ffsll((long long)m) - 1;
                int b = 0;
                if (rank == 0) b = atomicAdd(&cursor[ex], (int)__popcll(m));
                b = __shfl(b, leader, 64);
                int slot = padOff[ex] + b + rank;
                assignTok[slot] = t;
                tokSlot[2 * t + k] = slot;
            }
        }
    }
}

// ---------------- grouped GEMM A: h = silu(xb[tok] Wg^T) * (xb[tok] Wu^T) ----------------
// 256x128 tile, dbuf LDS, counted-vmcnt dual-barrier pipeline, slot-XOR swizzle, XCD swizzle.
__global__ __launch_bounds__(512) void gemmA_kernel(
        const unsigned short* __restrict__ xb,
        const unsigned short* __restrict__ gpb, const unsigned short* __restrict__ upb,
        const int* __restrict__ padOff, const int* __restrict__ assignTok,
        unsigned short* __restrict__ h) {
    int bid = blockIdx.x;
    int nid = (bid & 7) * 55 + (bid >> 3);          // 440 = 8 XCD * 55, bijective
    int colblk = nid / 40, rowblk = nid - colblk * 40;
    int pr0 = rowblk * 256;
    int n0 = colblk * 128;
    int e = -1;
#pragma unroll
    for (int i = 0; i < NE; ++i)
        if (pr0 >= padOff[i] && pr0 < padOff[i + 1]) e = i;
    if (e < 0) return;

    __shared__ unsigned short As[2][256 * 32];
    __shared__ unsigned short Bgs[2][128 * 32];
    __shared__ unsigned short Bus[2][128 * 32];

    int tid = threadIdx.x;
    int lane = tid & 63;
    int w = tid >> 6;
    int wm = (w >> 2) * 128;
    int wn = (w & 3) * 32;

    // write-side: inverse slot swizzle on the GLOBAL source (LDS dest stays linear)
    int aslot = (((lane & 3) ^ ((lane >> 3) & 3)) << 3);   // row = lane>>2 -> (row>>1)&3 = (lane>>3)&3
    int tok0 = assignTok[pr0 + w * 16 + (lane >> 2)];
    int tok1 = assignTok[pr0 + 128 + w * 16 + (lane >> 2)];
    const unsigned short* a0 = xb + (size_t)tok0 * DH + aslot;
    const unsigned short* a1 = xb + (size_t)tok1 * DH + aslot;
    int brow = n0 + (tid >> 2);
    int bslot = (((tid & 3) ^ ((tid >> 3) & 3)) << 3);     // row = tid>>2
    const unsigned short* gsrc = gpb + ((size_t)e * DI + brow) * DH + bslot;
    const unsigned short* usrc = upb + ((size_t)e * DI + brow) * DH + bslot;

    // read-side slot swizzle: q = lane>>4, row bits(2:1) = (lane>>1)&3
    int rq = (((lane >> 4) ^ ((lane >> 1) & 3)) << 3);

    f32x4 accG[8][2], accU[8][2];
#pragma unroll
    for (int i = 0; i < 8; ++i)
#pragma unroll
        for (int j = 0; j < 2; ++j) {
            accG[i][j] = (f32x4){0.f, 0.f, 0.f, 0.f};
            accU[i][j] = (f32x4){0.f, 0.f, 0.f, 0.f};
        }

#define STAGE_A(buf, k0) do { \
    GLDS(a0 + (k0),   &As[buf][w * 512]); \
    GLDS(a1 + (k0),   &As[buf][4096 + w * 512]); \
    GLDS(gsrc + (k0), &Bgs[buf][w * 512]); \
    GLDS(usrc + (k0), &Bus[buf][w * 512]); \
    } while (0)

#define KCOMP_A(cur, VMS) do { \
    asm volatile("s_waitcnt vmcnt(" VMS ")" ::: "memory"); \
    __builtin_amdgcn_s_barrier(); \
    __builtin_amdgcn_sched_barrier(0); \
    s16x8 af[8], bgf[2], bu2[2]; \
    _Pragma("unroll") \
    for (int i = 0; i < 8; ++i) \
        af[i] = *(const s16x8*)&As[cur][(wm + 16 * i + (lane & 15)) * 32 + rq]; \
    _Pragma("unroll") \
    for (int j = 0; j < 2; ++j) { \
        bgf[j] = *(const s16x8*)&Bgs[cur][(wn + 16 * j + (lane & 15)) * 32 + rq]; \
        bu2[j] = *(const s16x8*)&Bus[cur][(wn + 16 * j + (lane & 15)) * 32 + rq]; \
    } \
    asm volatile("s_waitcnt lgkmcnt(0)" ::: "memory"); \
    __builtin_amdgcn_sched_barrier(0); \
    __builtin_amdgcn_s_barrier(); \
    __builtin_amdgcn_sched_barrier(0); \
    _Pragma("unroll") \
    for (int i = 0; i < 8; ++i) \
        _Pragma("unroll") \
        for (int j = 0; j < 2; ++j) { \
            accG[i][j] = __builtin_amdgcn_mfma_f32_16x16x32_bf16(af[i], bgf[j], accG[i][j], 0, 0, 0); \
            accU[i][j] = __builtin_amdgcn_mfma_f32_16x16x32_bf16(af[i], bu2[j], accU[i][j], 0, 0, 0); \
        } \
    } while (0)

    STAGE_A(0, 0);
    for (int ks = 0; ks < 31; ++ks) {
        int cur = ks & 1;
        STAGE_A(cur ^ 1, (ks + 1) * 32);
        KCOMP_A(cur, "4");
    }
    KCOMP_A(1, "0");
#undef STAGE_A
#undef KCOMP_A

#pragma unroll
    for (int i = 0; i < 8; ++i) {
        int rowb = pr0 + wm + 16 * i + ((lane >> 4) << 2);
#pragma unroll
        for (int j = 0; j < 2; ++j) {
            int col = n0 + wn + 16 * j + (lane & 15);
#pragma unroll
            for (int r = 0; r < 4; ++r) {
                float g = accG[i][j][r], u = accU[i][j][r];
                float val = (g / (1.f + __expf(-g))) * u;
                h[(size_t)(rowb + r) * DI + col] = (unsigned short)f2bf(val);
            }
        }
    }
}

// ---------------- grouped GEMM B: outP = h Wd^T ----------------
__global__ __launch_bounds__(512) void gemmB_kernel(
        const unsigned short* __restrict__ h,
        const unsigned short* __restrict__ dpb,
        const int* __restrict__ padOff, const int* __restrict__ counts,
        float* __restrict__ outP) {
    int bid = blockIdx.x;
    int nid = (bid & 7) * 40 + (bid >> 3);          // 320 = 8 XCD * 40, bijective
    int colblk = nid / 40, rowblk = nid - colblk * 40;
    int pr0 = rowblk * 256;
    int n0 = colblk * 128;
    int e = -1, base = 0;
#pragma unroll
    for (int i = 0; i < NE; ++i)
        if (pr0 >= padOff[i] && pr0 < padOff[i + 1]) { e = i; base = padOff[i]; }
    if (e < 0) return;
    int cnt = counts[e];

    __shared__ unsigned short As[2][256 * 32];
    __shared__ unsigned short Bs[2][128 * 32];

    int tid = threadIdx.x;
    int lane = tid & 63;
    int w = tid >> 6;
    int wm = (w >> 2) * 128;
    int wn = (w & 3) * 32;

    int aslot = (((lane & 3) ^ ((lane >> 3) & 3)) << 3);
    const unsigned short* a0 = h + (size_t)(pr0 + w * 16 + (lane >> 2)) * DI + aslot;
    const unsigned short* a1 = h + (size_t)(pr0 + 128 + w * 16 + (lane >> 2)) * DI + aslot;
    int brow = n0 + (tid >> 2);
    int bslot = (((tid & 3) ^ ((tid >> 3) & 3)) << 3);
    const unsigned short* bsrc = dpb + ((size_t)e * DH + brow) * DI + bslot;

    int rq = (((lane >> 4) ^ ((lane >> 1) & 3)) << 3);

    f32x4 acc[8][2];
#pragma unroll
    for (int i = 0; i < 8; ++i)
#pragma unroll
        for (int j = 0; j < 2; ++j) acc[i][j] = (f32x4){0.f, 0.f, 0.f, 0.f};

#define STAGE_B(buf, k0) do { \
    GLDS(a0 + (k0),   &As[buf][w * 512]); \
    GLDS(a1 + (k0),   &As[buf][4096 + w * 512]); \
    GLDS(bsrc + (k0), &Bs[buf][w * 512]); \
    } while (0)

#define KCOMP_B(cur, VMS) do { \
    asm volatile("s_waitcnt vmcnt(" VMS ")" ::: "memory"); \
    __builtin_amdgcn_s_barrier(); \
    __builtin_amdgcn_sched_barrier(0); \
    s16x8 af[8], bf[2]; \
    _Pragma("unroll") \
    for (int i = 0; i < 8; ++i) \
        af[i] = *(const s16x8*)&As[cur][(wm + 16 * i + (lane & 15)) * 32 + rq]; \
    _Pragma("unroll") \
    for (int j = 0; j < 2; ++j) \
        bf[j] = *(const s16x8*)&Bs[cur][(wn + 16 * j + (lane & 15)) * 32 + rq]; \
    asm volatile("s_waitcnt lgkmcnt(0)" ::: "memory"); \
    __builtin_amdgcn_sched_barrier(0); \
    __builtin_amdgcn_s_barrier(); \
    __builtin_amdgcn_sched_barrier(0); \
    _Pragma("unroll") \
    for (int i = 0; i < 8; ++i) \
        _Pragma("unroll") \
        for (int j = 0; j < 2; ++j) \
            acc[i][j] = __builtin_amdgcn_mfma_f32_16x16x32_bf16(af[i], bf[j], acc[i][j], 0, 0, 0); \
    } while (0)

    STAGE_B(0, 0);
    for (int ks = 0; ks < 43; ++ks) {
        int cur = ks & 1;
        STAGE_B(cur ^ 1, (ks + 1) * 32);
        KCOMP_B(cur, "3");
    }
    KCOMP_B(1, "0");
#undef STAGE_B
#undef KCOMP_B

#pragma unroll
    for (int i = 0; i < 8; ++i) {
        int rowb = pr0 + wm + 16 * i + ((lane >> 4) << 2);
#pragma unroll
        for (int r = 0; r < 4; ++r) {
            int prow = rowb + r;
            if (prow - base < cnt) {
#pragma unroll
                for (int j = 0; j < 2; ++j) {
                    int col = n0 + wn + 16 * j + (lane & 15);
                    outP[(size_t)prow * DH + col] = acc[i][j][r];
                }
            }
        }
    }
}

// ---------------- combine: out[t] = w0*outP[s0] + w1*outP[s1] ----------------
__global__ __launch_bounds__(256) void combine_kernel(const float* __restrict__ outP,
        const int* __restrict__ tokSlot, const float* __restrict__ tokW,
        float* __restrict__ out) {
    int t = blockIdx.x;
    int c = threadIdx.x * 4;
    int s0 = tokSlot[2 * t], s1 = tokSlot[2 * t + 1];
    float w0 = tokW[2 * t], w1 = tokW[2 * t + 1];
    float4 a = *(const float4*)(outP + (size_t)s0 * DH + c);
    float4 b = *(const float4*)(outP + (size_t)s1 * DH + c);
    float4 o;
    o.x = w0 * a.x + w1 * b.x;
    o.y = w0 * a.y + w1 * b.y;
    o.z = w0 * a.z + w1 * b.z;
    o.w = w0 * a.w + w1 * b.w;
    *(float4*)(out + (size_t)t * DH + c) = o;
}

extern "C" void kernel_launch(void* const* d_in, const int* in_sizes, int n_in,
                              void* d_out, int out_size, void* d_ws, size_t ws_size,
                              hipStream_t stream) {
    const float* x  = (const float*)d_in[0];
    const float* gw = (const float*)d_in[1];
    const float* gp = (const float*)d_in[2];
    const float* up = (const float*)d_in[3];
    const float* dp = (const float*)d_in[4];
    float* out = (float*)d_out;
    float* logits = out + (size_t)T_TOK * DH;

    char* ws = (char*)d_ws;
    int*   counts    = (int*)(ws + 0);
    int*   cursor    = (int*)(ws + 64);
    int*   padOff    = (int*)(ws + 128);
    int*   tokE      = (int*)(ws + 4096);                       // 32 KB
    float* tokW      = (float*)(ws + 36864);                    // 32 KB
    int*   tokSlot   = (int*)(ws + 69632);                      // 32 KB
    int*   assignTok = (int*)(ws + 102400);                     // 40 KB (PADROWS ints)
    unsigned short* xb  = (unsigned short*)(ws + 147456);       // 8.39 MB
    unsigned short* gpb = (unsigned short*)(ws + 8536064);      // 23.07 MB
    unsigned short* upb = (unsigned short*)(ws + 31604736);     // 23.07 MB
    unsigned short* dpb = (unsigned short*)(ws + 54673408);     // 23.07 MB
    unsigned short* h   = (unsigned short*)(ws + 77742080);     // 28.84 MB
    float* outP = (float*)(ws + 8536064);  // 41.9 MB, overlaps gpb/upb (dead after gemmA)

    hipMemsetAsync(ws, 0, 256, stream);
    hipMemsetAsync(ws + 102400, 0, PADROWS * 4, stream);  // assignTok pad -> token 0

    const int NW4 = NE * DI * DH / 4;
    cvt3_kernel<<<dim3(1024, 3), 256, 0, stream>>>(gp, up, dp, gpb, upb, dpb, NW4);

    router_kernel<<<T_TOK / 4, 256, 0, stream>>>(x, gw, logits, tokE, tokW, xb);
    hist_kernel<<<1, 256, 0, stream>>>(tokE, counts, padOff);
    scatter_kernel<<<T_TOK / 256, 256, 0, stream>>>(tokE, padOff, cursor, assignTok, tokSlot);

    gemmA_kernel<<<dim3((DI / 128) * (PADROWS / 256)), 512, 0, stream>>>(xb, gpb, upb, padOff, assignTok, h);
    gemmB_kernel<<<dim3((DH / 128) * (PADROWS / 256)), 512, 0, stream>>>(h, dpb, padOff, counts, outP);
    combine_kernel<<<T_TOK, 256, 0, stream>>>(outP, tokSlot, tokW, out);
}

// Round 7
// 231.701 us; speedup vs baseline: 1.0331x; 1.0331x over previous
//
#include <hip/hip_runtime.h>
#include <hip/hip_bf16.h>
#include <stdint.h>

#define T_TOK 4096
#define DH 1024
#define DI 1408
#define NE 8
#define TOPK 2
#define PADROWS 10240   // 8192 assignments + up to 8*255 pad (256-row tiles)

typedef short s16x8 __attribute__((ext_vector_type(8)));
typedef float f32x4 __attribute__((ext_vector_type(4)));

__device__ inline unsigned f2bf(float f) {
    __hip_bfloat16 h = __float2bfloat16(f);
    return (unsigned)*(unsigned short*)&h;
}
__device__ inline float bf2f(unsigned short u) {
    return __uint_as_float(((unsigned)u) << 16);
}

#define GLDS(src, dst) __builtin_amdgcn_global_load_lds( \
    (const __attribute__((address_space(1))) void*)(src), \
    (__attribute__((address_space(3))) void*)(dst), 16, 0, 0)

// ---------------- router: logits, softmax, top-2, renorm; x->bf16. NO atomics ----------------
__global__ __launch_bounds__(256) void router_kernel(const float* __restrict__ x,
                              const float* __restrict__ gw,
                              float* __restrict__ logits_out,
                              int* __restrict__ tokE, float* __restrict__ tokW,
                              unsigned short* __restrict__ xb) {
    int wave = threadIdx.x >> 6;
    int lane = threadIdx.x & 63;
    int t = blockIdx.x * 4 + wave;
    const float4* xr = (const float4*)(x + (size_t)t * DH);

    float acc[NE];
#pragma unroll
    for (int e = 0; e < NE; ++e) acc[e] = 0.f;

#pragma unroll
    for (int i = 0; i < 4; ++i) {
        float4 xv = xr[lane + i * 64];
#pragma unroll
        for (int e = 0; e < NE; ++e) {
            float4 g = ((const float4*)(gw + (size_t)e * DH))[lane + i * 64];
            acc[e] += xv.x * g.x + xv.y * g.y + xv.z * g.z + xv.w * g.w;
        }
        uint2 o;
        o.x = f2bf(xv.x) | (f2bf(xv.y) << 16);
        o.y = f2bf(xv.z) | (f2bf(xv.w) << 16);
        *(uint2*)(xb + (size_t)t * DH + (lane + i * 64) * 4) = o;
    }
#pragma unroll
    for (int e = 0; e < NE; ++e) {
#pragma unroll
        for (int off = 32; off > 0; off >>= 1) acc[e] += __shfl_xor(acc[e], off, 64);
    }
    if (lane == 0) {
        float mx = acc[0];
#pragma unroll
        for (int e = 1; e < NE; ++e) mx = fmaxf(mx, acc[e]);
        float p[NE]; float s = 0.f;
#pragma unroll
        for (int e = 0; e < NE; ++e) { p[e] = expf(acc[e] - mx); s += p[e]; }
        float inv = 1.f / s;
#pragma unroll
        for (int e = 0; e < NE; ++e) p[e] *= inv;
        int i0 = 0, i1 = -1; float p0 = -1.f, p1 = -1.f;
#pragma unroll
        for (int e = 0; e < NE; ++e) {
            float v = p[e];
            if (v > p0) { p1 = p0; i1 = i0; p0 = v; i0 = e; }
            else if (v > p1) { p1 = v; i1 = e; }
        }
        float wsum = p0 + p1;
#pragma unroll
        for (int e = 0; e < NE; ++e) logits_out[(size_t)t * NE + e] = acc[e];
        tokE[2 * t]     = i0;  tokE[2 * t + 1] = i1;
        tokW[2 * t]     = p0 / wsum;  tokW[2 * t + 1] = p1 / wsum;
    }
}

// ---------------- histogram + prefix (pad 256): single block ----------------
__global__ __launch_bounds__(256) void hist_kernel(const int* __restrict__ tokE,
        int* __restrict__ counts, int* __restrict__ padOff) {
    __shared__ int wc[4][NE];
    int tid = threadIdx.x;
    int wave = tid >> 6, lane = tid & 63;
    int cnt[NE];
#pragma unroll
    for (int e = 0; e < NE; ++e) cnt[e] = 0;
    for (int i = tid; i < T_TOK * TOPK; i += 256) {
        int v = tokE[i];
#pragma unroll
        for (int e = 0; e < NE; ++e)
            cnt[e] += (int)__popcll(__ballot(v == e));
    }
    if (lane == 0) {
#pragma unroll
        for (int e = 0; e < NE; ++e) wc[wave][e] = cnt[e];
    }
    __syncthreads();
    if (tid == 0) {
        int r = 0;
        for (int e = 0; e < NE; ++e) {
            int c = wc[0][e] + wc[1][e] + wc[2][e] + wc[3][e];
            counts[e] = c;
            padOff[e] = r;
            r += ((c + 255) >> 8) << 8;
        }
        padOff[NE] = r;
    }
}

// ---------------- scatter: wave-aggregated cursor atomics ----------------
__global__ __launch_bounds__(256) void scatter_kernel(const int* __restrict__ tokE,
                               const int* __restrict__ padOff, int* __restrict__ cursor,
                               int* __restrict__ assignTok, int* __restrict__ tokSlot) {
    int t = blockIdx.x * blockDim.x + threadIdx.x;
    int lane = threadIdx.x & 63;
    unsigned long long lmask = (1ull << lane) - 1ull;
#pragma unroll
    for (int k = 0; k < TOPK; ++k) {
        int e = tokE[2 * t + k];
#pragma unroll
        for (int ex = 0; ex < NE; ++ex) {
            unsigned long long m = __ballot(e == ex);
            if (e == ex) {
                int rank = (int)__popcll(m & lmask);
                int leader = __ffsll((long long)m) - 1;
                int b = 0;
                if (rank == 0) b = atomicAdd(&cursor[ex], (int)__popcll(m));
                b = __shfl(b, leader, 64);
                int slot = padOff[ex] + b + rank;
                assignTok[slot] = t;
                tokSlot[2 * t + k] = slot;
            }
        }
    }
}

// ---------------- grouped GEMM A: h = silu(xb[tok] Wg^T) * (xb[tok] Wu^T) ----------------
// 256x128 tile, dbuf LDS; A via GLDS (pre-swizzled source); B reg-staged from fp32
// with in-register cvt + swizzled ds_write. XCD-aware block swizzle.
__global__ __launch_bounds__(512) void gemmA_kernel(
        const unsigned short* __restrict__ xb,
        const float* __restrict__ gp, const float* __restrict__ up,
        const int* __restrict__ padOff, const int* __restrict__ assignTok,
        unsigned short* __restrict__ h) {
    int bid = blockIdx.x;
    int nid = (bid & 7) * 55 + (bid >> 3);          // 440 = 8 XCD * 55, bijective
    int colblk = nid / 40, rowblk = nid - colblk * 40;
    int pr0 = rowblk * 256;
    int n0 = colblk * 128;
    int e = -1;
#pragma unroll
    for (int i = 0; i < NE; ++i)
        if (pr0 >= padOff[i] && pr0 < padOff[i + 1]) e = i;
    if (e < 0) return;

    __shared__ unsigned short As[2][256 * 32];
    __shared__ unsigned short Bgs[2][128 * 32];
    __shared__ unsigned short Bus[2][128 * 32];

    int tid = threadIdx.x;
    int lane = tid & 63;
    int w = tid >> 6;
    int wm = (w >> 2) * 128;
    int wn = (w & 3) * 32;

    // A: GLDS, inverse slot swizzle on the GLOBAL source (LDS dest stays linear)
    int aslot = (((lane & 3) ^ ((lane >> 3) & 3)) << 3);
    int tok0 = assignTok[pr0 + w * 16 + (lane >> 2)];
    int tok1 = assignTok[pr0 + 128 + w * 16 + (lane >> 2)];
    const unsigned short* a0 = xb + (size_t)tok0 * DH + aslot;
    const unsigned short* a1 = xb + (size_t)tok1 * DH + aslot;

    // B: reg-staged fp32->bf16, swizzled ds_write. thread t: row=t>>2, quad=t&3
    int brow = tid >> 2;
    int qd = tid & 3;
    const float* gsrc = gp + ((size_t)e * DI + n0 + brow) * DH + qd * 8;
    const float* usrc = up + ((size_t)e * DI + n0 + brow) * DH + qd * 8;
    int bphys = (qd ^ ((brow >> 1) & 3)) << 3;
    int boff = brow * 32 + bphys;     // shorts within a buffer

    // read-side slot swizzle
    int rq = (((lane >> 4) ^ ((lane >> 1) & 3)) << 3);

    f32x4 accG[8][2], accU[8][2];
#pragma unroll
    for (int i = 0; i < 8; ++i)
#pragma unroll
        for (int j = 0; j < 2; ++j) {
            accG[i][j] = (f32x4){0.f, 0.f, 0.f, 0.f};
            accU[i][j] = (f32x4){0.f, 0.f, 0.f, 0.f};
        }

#define PACK8(d, va, vb) do { \
    d[0] = (short)f2bf(va.x); d[1] = (short)f2bf(va.y); \
    d[2] = (short)f2bf(va.z); d[3] = (short)f2bf(va.w); \
    d[4] = (short)f2bf(vb.x); d[5] = (short)f2bf(vb.y); \
    d[6] = (short)f2bf(vb.z); d[7] = (short)f2bf(vb.w); \
    } while (0)

    // prologue: stage tile 0
    {
        GLDS(a0, &As[0][w * 512]);
        GLDS(a1, &As[0][4096 + w * 512]);
        float4 ga = *(const float4*)(gsrc);
        float4 gb = *(const float4*)(gsrc + 4);
        float4 ua = *(const float4*)(usrc);
        float4 ub = *(const float4*)(usrc + 4);
        s16x8 pg, pu;
        PACK8(pg, ga, gb); PACK8(pu, ua, ub);
        *(s16x8*)&Bgs[0][boff] = pg;
        *(s16x8*)&Bus[0][boff] = pu;
    }
    __syncthreads();

    for (int ks = 0; ks < 32; ++ks) {
        int cur = ks & 1;
        float4 ga, gb, ua, ub;
        if (ks < 31) {
            int k0 = (ks + 1) * 32;
            GLDS(a0 + k0, &As[cur ^ 1][w * 512]);
            GLDS(a1 + k0, &As[cur ^ 1][4096 + w * 512]);
            ga = *(const float4*)(gsrc + k0);
            gb = *(const float4*)(gsrc + k0 + 4);
            ua = *(const float4*)(usrc + k0);
            ub = *(const float4*)(usrc + k0 + 4);
        }

        s16x8 af[8], bgf[2], bu2[2];
#pragma unroll
        for (int i = 0; i < 8; ++i)
            af[i] = *(const s16x8*)&As[cur][(wm + 16 * i + (lane & 15)) * 32 + rq];
#pragma unroll
        for (int j = 0; j < 2; ++j) {
            bgf[j] = *(const s16x8*)&Bgs[cur][(wn + 16 * j + (lane & 15)) * 32 + rq];
            bu2[j] = *(const s16x8*)&Bus[cur][(wn + 16 * j + (lane & 15)) * 32 + rq];
        }
#pragma unroll
        for (int i = 0; i < 8; ++i)
#pragma unroll
            for (int j = 0; j < 2; ++j) {
                accG[i][j] = __builtin_amdgcn_mfma_f32_16x16x32_bf16(af[i], bgf[j], accG[i][j], 0, 0, 0);
                accU[i][j] = __builtin_amdgcn_mfma_f32_16x16x32_bf16(af[i], bu2[j], accU[i][j], 0, 0, 0);
            }

        if (ks < 31) {
            s16x8 pg, pu;
            PACK8(pg, ga, gb); PACK8(pu, ua, ub);
            *(s16x8*)&Bgs[cur ^ 1][boff] = pg;
            *(s16x8*)&Bus[cur ^ 1][boff] = pu;
        }
        __syncthreads();
    }

#pragma unroll
    for (int i = 0; i < 8; ++i) {
        int rowb = pr0 + wm + 16 * i + ((lane >> 4) << 2);
#pragma unroll
        for (int j = 0; j < 2; ++j) {
            int col = n0 + wn + 16 * j + (lane & 15);
#pragma unroll
            for (int r = 0; r < 4; ++r) {
                float g = accG[i][j][r], u = accU[i][j][r];
                float val = (g / (1.f + __expf(-g))) * u;
                h[(size_t)(rowb + r) * DI + col] = (unsigned short)f2bf(val);
            }
        }
    }
}

// ---------------- grouped GEMM B: outP(bf16) = h Wd^T ----------------
__global__ __launch_bounds__(512) void gemmB_kernel(
        const unsigned short* __restrict__ h,
        const float* __restrict__ dp,
        const int* __restrict__ padOff, const int* __restrict__ counts,
        unsigned short* __restrict__ outP) {
    int bid = blockIdx.x;
    int nid = (bid & 7) * 40 + (bid >> 3);          // 320 = 8 XCD * 40, bijective
    int colblk = nid / 40, rowblk = nid - colblk * 40;
    int pr0 = rowblk * 256;
    int n0 = colblk * 128;
    int e = -1, base = 0;
#pragma unroll
    for (int i = 0; i < NE; ++i)
        if (pr0 >= padOff[i] && pr0 < padOff[i + 1]) { e = i; base = padOff[i]; }
    if (e < 0) return;
    int cnt = counts[e];

    __shared__ unsigned short As[2][256 * 32];
    __shared__ unsigned short Bs[2][128 * 32];

    int tid = threadIdx.x;
    int lane = tid & 63;
    int w = tid >> 6;
    int wm = (w >> 2) * 128;
    int wn = (w & 3) * 32;

    int aslot = (((lane & 3) ^ ((lane >> 3) & 3)) << 3);
    const unsigned short* a0 = h + (size_t)(pr0 + w * 16 + (lane >> 2)) * DI + aslot;
    const unsigned short* a1 = h + (size_t)(pr0 + 128 + w * 16 + (lane >> 2)) * DI + aslot;

    int brow = tid >> 2;
    int qd = tid & 3;
    const float* bsrc = dp + ((size_t)e * DH + n0 + brow) * DI + qd * 8;
    int bphys = (qd ^ ((brow >> 1) & 3)) << 3;
    int boff = brow * 32 + bphys;

    int rq = (((lane >> 4) ^ ((lane >> 1) & 3)) << 3);

    f32x4 acc[8][2];
#pragma unroll
    for (int i = 0; i < 8; ++i)
#pragma unroll
        for (int j = 0; j < 2; ++j) acc[i][j] = (f32x4){0.f, 0.f, 0.f, 0.f};

    {
        GLDS(a0, &As[0][w * 512]);
        GLDS(a1, &As[0][4096 + w * 512]);
        float4 da = *(const float4*)(bsrc);
        float4 db = *(const float4*)(bsrc + 4);
        s16x8 pd;
        PACK8(pd, da, db);
        *(s16x8*)&Bs[0][boff] = pd;
    }
    __syncthreads();

    for (int ks = 0; ks < 44; ++ks) {
        int cur = ks & 1;
        float4 da, db;
        if (ks < 43) {
            int k0 = (ks + 1) * 32;
            GLDS(a0 + k0, &As[cur ^ 1][w * 512]);
            GLDS(a1 + k0, &As[cur ^ 1][4096 + w * 512]);
            da = *(const float4*)(bsrc + k0);
            db = *(const float4*)(bsrc + k0 + 4);
        }

        s16x8 af[8], bf[2];
#pragma unroll
        for (int i = 0; i < 8; ++i)
            af[i] = *(const s16x8*)&As[cur][(wm + 16 * i + (lane & 15)) * 32 + rq];
#pragma unroll
        for (int j = 0; j < 2; ++j)
            bf[j] = *(const s16x8*)&Bs[cur][(wn + 16 * j + (lane & 15)) * 32 + rq];
#pragma unroll
        for (int i = 0; i < 8; ++i)
#pragma unroll
            for (int j = 0; j < 2; ++j)
                acc[i][j] = __builtin_amdgcn_mfma_f32_16x16x32_bf16(af[i], bf[j], acc[i][j], 0, 0, 0);

        if (ks < 43) {
            s16x8 pd;
            PACK8(pd, da, db);
            *(s16x8*)&Bs[cur ^ 1][boff] = pd;
        }
        __syncthreads();
    }

#pragma unroll
    for (int i = 0; i < 8; ++i) {
        int rowb = pr0 + wm + 16 * i + ((lane >> 4) << 2);
#pragma unroll
        for (int r = 0; r < 4; ++r) {
            int prow = rowb + r;
            if (prow - base < cnt) {
#pragma unroll
                for (int j = 0; j < 2; ++j) {
                    int col = n0 + wn + 16 * j + (lane & 15);
                    outP[(size_t)prow * DH + col] = (unsigned short)f2bf(acc[i][j][r]);
                }
            }
        }
    }
}

// ---------------- combine: out[t] = w0*outP[s0] + w1*outP[s1] (bf16 in, fp32 out) ----------------
__global__ __launch_bounds__(256) void combine_kernel(const unsigned short* __restrict__ outP,
        const int* __restrict__ tokSlot, const float* __restrict__ tokW,
        float* __restrict__ out) {
    int t = blockIdx.x;
    int c = threadIdx.x * 4;
    int s0 = tokSlot[2 * t], s1 = tokSlot[2 * t + 1];
    float w0 = tokW[2 * t], w1 = tokW[2 * t + 1];
    ushort4 a = *(const ushort4*)(outP + (size_t)s0 * DH + c);
    ushort4 b = *(const ushort4*)(outP + (size_t)s1 * DH + c);
    float4 o;
    o.x = w0 * bf2f(a.x) + w1 * bf2f(b.x);
    o.y = w0 * bf2f(a.y) + w1 * bf2f(b.y);
    o.z = w0 * bf2f(a.z) + w1 * bf2f(b.z);
    o.w = w0 * bf2f(a.w) + w1 * bf2f(b.w);
    *(float4*)(out + (size_t)t * DH + c) = o;
}

extern "C" void kernel_launch(void* const* d_in, const int* in_sizes, int n_in,
                              void* d_out, int out_size, void* d_ws, size_t ws_size,
                              hipStream_t stream) {
    const float* x  = (const float*)d_in[0];
    const float* gw = (const float*)d_in[1];
    const float* gp = (const float*)d_in[2];
    const float* up = (const float*)d_in[3];
    const float* dp = (const float*)d_in[4];
    float* out = (float*)d_out;
    float* logits = out + (size_t)T_TOK * DH;

    char* ws = (char*)d_ws;
    int*   counts    = (int*)(ws + 0);
    int*   cursor    = (int*)(ws + 64);
    int*   padOff    = (int*)(ws + 128);
    int*   tokE      = (int*)(ws + 4096);                       // 32 KB
    float* tokW      = (float*)(ws + 36864);                    // 32 KB
    int*   tokSlot   = (int*)(ws + 69632);                      // 32 KB
    int*   assignTok = (int*)(ws + 102400);                     // 40 KB (PADROWS ints)
    unsigned short* xb   = (unsigned short*)(ws + 147456);      // 8.39 MB
    unsigned short* h    = (unsigned short*)(ws + 8536064);     // 28.84 MB
    unsigned short* outP = (unsigned short*)(ws + 37376000);    // 20.97 MB

    hipMemsetAsync(ws, 0, 256, stream);
    hipMemsetAsync(ws + 102400, 0, PADROWS * 4, stream);  // assignTok pad -> token 0

    router_kernel<<<T_TOK / 4, 256, 0, stream>>>(x, gw, logits, tokE, tokW, xb);
    hist_kernel<<<1, 256, 0, stream>>>(tokE, counts, padOff);
    scatter_kernel<<<T_TOK / 256, 256, 0, stream>>>(tokE, padOff, cursor, assignTok, tokSlot);

    gemmA_kernel<<<dim3((DI / 128) * (PADROWS / 256)), 512, 0, stream>>>(xb, gp, up, padOff, assignTok, h);
    gemmB_kernel<<<dim3((DH / 128) * (PADROWS / 256)), 512, 0, stream>>>(h, dp, padOff, counts, outP);
    combine_kernel<<<T_TOK, 256, 0, stream>>>(outP, tokSlot, tokW, out);
}

// Round 8
// 188.188 us; speedup vs baseline: 1.2719x; 1.2312x over previous
//
#include <hip/hip_runtime.h>
#include <hip/hip_bf16.h>
#include <stdint.h>

#define T_TOK 4096
#define DH 1024
#define DI 1408
#define NE 8
#define TOPK 2
#define PADROWS 9216   // 8192 assignments + up to 8*127 pad (128-row tiles)

typedef short s16x8 __attribute__((ext_vector_type(8)));
typedef float f32x4 __attribute__((ext_vector_type(4)));

__device__ inline unsigned f2bf(float f) {
    __hip_bfloat16 h = __float2bfloat16(f);
    return (unsigned)*(unsigned short*)&h;
}
__device__ inline float bf2f(unsigned short u) {
    return __uint_as_float(((unsigned)u) << 16);
}

#define GLDS(src, dst) __builtin_amdgcn_global_load_lds( \
    (const __attribute__((address_space(1))) void*)(src), \
    (__attribute__((address_space(3))) void*)(dst), 16, 0, 0)

// ---------------- fp32 -> bf16 bulk convert (3 weight tensors, one launch) ----------------
__global__ __launch_bounds__(256) void cvt3_kernel(const float* __restrict__ s0,
        const float* __restrict__ s1, const float* __restrict__ s2,
        unsigned short* __restrict__ t0, unsigned short* __restrict__ t1,
        unsigned short* __restrict__ t2, int n4) {
    const float* src = blockIdx.y == 0 ? s0 : (blockIdx.y == 1 ? s1 : s2);
    unsigned short* dst = blockIdx.y == 0 ? t0 : (blockIdx.y == 1 ? t1 : t2);
    int i = blockIdx.x * blockDim.x + threadIdx.x;
    int stride = gridDim.x * blockDim.x;
    for (; i < n4; i += stride) {
        float4 v = ((const float4*)src)[i];
        uint2 o;
        o.x = f2bf(v.x) | (f2bf(v.y) << 16);
        o.y = f2bf(v.z) | (f2bf(v.w) << 16);
        ((uint2*)dst)[i] = o;
    }
}

// ---------------- router: logits, softmax, top-2, renorm; x->bf16. NO atomics ----------------
__global__ __launch_bounds__(256) void router_kernel(const float* __restrict__ x,
                              const float* __restrict__ gw,
                              float* __restrict__ logits_out,
                              int* __restrict__ tokE, float* __restrict__ tokW,
                              unsigned short* __restrict__ xb) {
    int wave = threadIdx.x >> 6;
    int lane = threadIdx.x & 63;
    int t = blockIdx.x * 4 + wave;
    const float4* xr = (const float4*)(x + (size_t)t * DH);

    float acc[NE];
#pragma unroll
    for (int e = 0; e < NE; ++e) acc[e] = 0.f;

#pragma unroll
    for (int i = 0; i < 4; ++i) {
        float4 xv = xr[lane + i * 64];
#pragma unroll
        for (int e = 0; e < NE; ++e) {
            float4 g = ((const float4*)(gw + (size_t)e * DH))[lane + i * 64];
            acc[e] += xv.x * g.x + xv.y * g.y + xv.z * g.z + xv.w * g.w;
        }
        uint2 o;
        o.x = f2bf(xv.x) | (f2bf(xv.y) << 16);
        o.y = f2bf(xv.z) | (f2bf(xv.w) << 16);
        *(uint2*)(xb + (size_t)t * DH + (lane + i * 64) * 4) = o;
    }
#pragma unroll
    for (int e = 0; e < NE; ++e) {
#pragma unroll
        for (int off = 32; off > 0; off >>= 1) acc[e] += __shfl_xor(acc[e], off, 64);
    }
    if (lane == 0) {
        float mx = acc[0];
#pragma unroll
        for (int e = 1; e < NE; ++e) mx = fmaxf(mx, acc[e]);
        float p[NE]; float s = 0.f;
#pragma unroll
        for (int e = 0; e < NE; ++e) { p[e] = expf(acc[e] - mx); s += p[e]; }
        float inv = 1.f / s;
#pragma unroll
        for (int e = 0; e < NE; ++e) p[e] *= inv;
        int i0 = 0, i1 = -1; float p0 = -1.f, p1 = -1.f;
#pragma unroll
        for (int e = 0; e < NE; ++e) {
            float v = p[e];
            if (v > p0) { p1 = p0; i1 = i0; p0 = v; i0 = e; }
            else if (v > p1) { p1 = v; i1 = e; }
        }
        float wsum = p0 + p1;
#pragma unroll
        for (int e = 0; e < NE; ++e) logits_out[(size_t)t * NE + e] = acc[e];
        tokE[2 * t]     = i0;  tokE[2 * t + 1] = i1;
        tokW[2 * t]     = p0 / wsum;  tokW[2 * t + 1] = p1 / wsum;
    }
}

// ---------------- hist + prefix + scatter: ONE single-block kernel, LDS cursor ----------------
__global__ __launch_bounds__(1024) void histscatter_kernel(const int* __restrict__ tokE,
        int* __restrict__ countsG, int* __restrict__ padOffG,
        int* __restrict__ assignTok, int* __restrict__ tokSlot) {
    __shared__ int wc[16][NE];
    __shared__ int padOff[NE + 1];
    __shared__ int cursor[NE];
    int tid = threadIdx.x, wave = tid >> 6, lane = tid & 63;

    int cnt[NE];
#pragma unroll
    for (int e = 0; e < NE; ++e) cnt[e] = 0;
    for (int i = tid; i < T_TOK * TOPK; i += 1024) {
        int v = tokE[i];
#pragma unroll
        for (int e = 0; e < NE; ++e)
            cnt[e] += (int)__popcll(__ballot(v == e));
    }
    if (lane == 0) {
#pragma unroll
        for (int e = 0; e < NE; ++e) wc[wave][e] = cnt[e];
    }
    __syncthreads();
    if (tid == 0) {
        int r = 0;
        for (int e = 0; e < NE; ++e) {
            int c = 0;
            for (int w = 0; w < 16; ++w) c += wc[w][e];
            countsG[e] = c;
            padOff[e] = r;
            padOffG[e] = r;
            cursor[e] = 0;
            r += ((c + 127) >> 7) << 7;
        }
        padOff[NE] = r;
        padOffG[NE] = r;
    }
    __syncthreads();

    unsigned long long lmask = (1ull << lane) - 1ull;
    for (int i = tid; i < T_TOK * TOPK; i += 1024) {
        int e = tokE[i];
#pragma unroll
        for (int ex = 0; ex < NE; ++ex) {
            unsigned long long m = __ballot(e == ex);
            if (e == ex) {
                int rank = (int)__popcll(m & lmask);
                int leader = __ffsll((long long)m) - 1;
                int b = 0;
                if (rank == 0) b = atomicAdd(&cursor[ex], (int)__popcll(m));
                b = __shfl(b, leader, 64);
                int slot = padOff[ex] + b + rank;
                assignTok[slot] = i >> 1;
                tokSlot[i] = slot;
            }
        }
    }
}

// ---------------- grouped GEMM A: h = silu(xb[tok] Wg^T) * (xb[tok] Wu^T) ----------------
// 128x128 tile, dbuf LDS, counted-vmcnt pipeline, slot-XOR swizzle, XCD swizzle.
__global__ __launch_bounds__(512) void gemmA_kernel(
        const unsigned short* __restrict__ xb,
        const unsigned short* __restrict__ gpb, const unsigned short* __restrict__ upb,
        const int* __restrict__ padOff, const int* __restrict__ assignTok,
        unsigned short* __restrict__ h) {
    int bid = blockIdx.x;
    int nid = (bid & 7) * 99 + (bid >> 3);          // 792 = 8 XCD * 99, bijective
    int colblk = nid / 72, rowblk = nid - colblk * 72;
    int pr0 = rowblk * 128;
    int n0 = colblk * 128;
    int e = -1;
#pragma unroll
    for (int i = 0; i < NE; ++i)
        if (pr0 >= padOff[i] && pr0 < padOff[i + 1]) e = i;
    if (e < 0) return;

    __shared__ unsigned short As[2][128 * 32];    // 8 KB each
    __shared__ unsigned short Bgs[2][128 * 32];
    __shared__ unsigned short Bus[2][128 * 32];   // 48 KB total

    int tid = threadIdx.x;
    int lane = tid & 63;
    int w = tid >> 6;
    int wm = (w >> 2) * 64;     // wave M offset (0/64)
    int wn = (w & 3) * 32;      // wave N offset (0/32/64/96)

    // staging: wave w stages rows [w*16, w*16+16); inverse slot swizzle on global source
    int srow = w * 16 + (lane >> 2);
    int aslot = (((lane & 3) ^ ((lane >> 3) & 3)) << 3);
    int tok = assignTok[pr0 + srow];
    const unsigned short* a0   = xb  + (size_t)tok * DH + aslot;
    const unsigned short* gsrc = gpb + ((size_t)e * DI + n0 + srow) * DH + aslot;
    const unsigned short* usrc = upb + ((size_t)e * DI + n0 + srow) * DH + aslot;
    int sdst = w * 512;   // shorts

    // read-side slot swizzle
    int rq = (((lane >> 4) ^ ((lane >> 1) & 3)) << 3);

    f32x4 accG[4][2], accU[4][2];
#pragma unroll
    for (int i = 0; i < 4; ++i)
#pragma unroll
        for (int j = 0; j < 2; ++j) {
            accG[i][j] = (f32x4){0.f, 0.f, 0.f, 0.f};
            accU[i][j] = (f32x4){0.f, 0.f, 0.f, 0.f};
        }

#define STAGE_A(buf, k0) do { \
    GLDS(a0 + (k0),   &As[buf][sdst]); \
    GLDS(gsrc + (k0), &Bgs[buf][sdst]); \
    GLDS(usrc + (k0), &Bus[buf][sdst]); \
    } while (0)

#define KCOMP_A(cur, VMS) do { \
    asm volatile("s_waitcnt vmcnt(" VMS ")" ::: "memory"); \
    __builtin_amdgcn_s_barrier(); \
    __builtin_amdgcn_sched_barrier(0); \
    s16x8 af[4], bgf[2], bu2[2]; \
    _Pragma("unroll") \
    for (int i = 0; i < 4; ++i) \
        af[i] = *(const s16x8*)&As[cur][(wm + 16 * i + (lane & 15)) * 32 + rq]; \
    _Pragma("unroll") \
    for (int j = 0; j < 2; ++j) { \
        bgf[j] = *(const s16x8*)&Bgs[cur][(wn + 16 * j + (lane & 15)) * 32 + rq]; \
        bu2[j] = *(const s16x8*)&Bus[cur][(wn + 16 * j + (lane & 15)) * 32 + rq]; \
    } \
    asm volatile("s_waitcnt lgkmcnt(0)" ::: "memory"); \
    __builtin_amdgcn_sched_barrier(0); \
    __builtin_amdgcn_s_barrier(); \
    __builtin_amdgcn_sched_barrier(0); \
    _Pragma("unroll") \
    for (int i = 0; i < 4; ++i) \
        _Pragma("unroll") \
        for (int j = 0; j < 2; ++j) { \
            accG[i][j] = __builtin_amdgcn_mfma_f32_16x16x32_bf16(af[i], bgf[j], accG[i][j], 0, 0, 0); \
            accU[i][j] = __builtin_amdgcn_mfma_f32_16x16x32_bf16(af[i], bu2[j], accU[i][j], 0, 0, 0); \
        } \
    } while (0)

    STAGE_A(0, 0);
    for (int ks = 0; ks < 31; ++ks) {
        STAGE_A((ks + 1) & 1, (ks + 1) * 32);
        KCOMP_A(ks & 1, "3");
    }
    KCOMP_A(1, "0");
#undef STAGE_A
#undef KCOMP_A

#pragma unroll
    for (int i = 0; i < 4; ++i) {
        int rowb = pr0 + wm + 16 * i + ((lane >> 4) << 2);
#pragma unroll
        for (int j = 0; j < 2; ++j) {
            int col = n0 + wn + 16 * j + (lane & 15);
#pragma unroll
            for (int r = 0; r < 4; ++r) {
                float g = accG[i][j][r], u = accU[i][j][r];
                float val = (g / (1.f + __expf(-g))) * u;
                h[(size_t)(rowb + r) * DI + col] = (unsigned short)f2bf(val);
            }
        }
    }
}

// ---------------- grouped GEMM B: outP(bf16) = h Wd^T ----------------
__global__ __launch_bounds__(512) void gemmB_kernel(
        const unsigned short* __restrict__ h,
        const unsigned short* __restrict__ dpb,
        const int* __restrict__ padOff, const int* __restrict__ counts,
        unsigned short* __restrict__ outP) {
    int bid = blockIdx.x;
    int nid = (bid & 7) * 72 + (bid >> 3);          // 576 = 8 XCD * 72, bijective
    int colblk = nid / 72, rowblk = nid - colblk * 72;  // colblk == bid&7: one col panel per XCD
    int pr0 = rowblk * 128;
    int n0 = colblk * 128;
    int e = -1, base = 0;
#pragma unroll
    for (int i = 0; i < NE; ++i)
        if (pr0 >= padOff[i] && pr0 < padOff[i + 1]) { e = i; base = padOff[i]; }
    if (e < 0) return;
    int cnt = counts[e];

    __shared__ unsigned short As[2][128 * 32];
    __shared__ unsigned short Bs[2][128 * 32];      // 32 KB total

    int tid = threadIdx.x;
    int lane = tid & 63;
    int w = tid >> 6;
    int wm = (w >> 2) * 64;
    int wn = (w & 3) * 32;

    int srow = w * 16 + (lane >> 2);
    int aslot = (((lane & 3) ^ ((lane >> 3) & 3)) << 3);
    const unsigned short* a0   = h   + (size_t)(pr0 + srow) * DI + aslot;
    const unsigned short* bsrc = dpb + ((size_t)e * DH + n0 + srow) * DI + aslot;
    int sdst = w * 512;

    int rq = (((lane >> 4) ^ ((lane >> 1) & 3)) << 3);

    f32x4 acc[4][2];
#pragma unroll
    for (int i = 0; i < 4; ++i)
#pragma unroll
        for (int j = 0; j < 2; ++j) acc[i][j] = (f32x4){0.f, 0.f, 0.f, 0.f};

#define STAGE_B(buf, k0) do { \
    GLDS(a0 + (k0),   &As[buf][sdst]); \
    GLDS(bsrc + (k0), &Bs[buf][sdst]); \
    } while (0)

#define KCOMP_B(cur, VMS) do { \
    asm volatile("s_waitcnt vmcnt(" VMS ")" ::: "memory"); \
    __builtin_amdgcn_s_barrier(); \
    __builtin_amdgcn_sched_barrier(0); \
    s16x8 af[4], bf[2]; \
    _Pragma("unroll") \
    for (int i = 0; i < 4; ++i) \
        af[i] = *(const s16x8*)&As[cur][(wm + 16 * i + (lane & 15)) * 32 + rq]; \
    _Pragma("unroll") \
    for (int j = 0; j < 2; ++j) \
        bf[j] = *(const s16x8*)&Bs[cur][(wn + 16 * j + (lane & 15)) * 32 + rq]; \
    asm volatile("s_waitcnt lgkmcnt(0)" ::: "memory"); \
    __builtin_amdgcn_sched_barrier(0); \
    __builtin_amdgcn_s_barrier(); \
    __builtin_amdgcn_sched_barrier(0); \
    _Pragma("unroll") \
    for (int i = 0; i < 4; ++i) \
        _Pragma("unroll") \
        for (int j = 0; j < 2; ++j) \
            acc[i][j] = __builtin_amdgcn_mfma_f32_16x16x32_bf16(af[i], bf[j], acc[i][j], 0, 0, 0); \
    } while (0)

    STAGE_B(0, 0);
    for (int ks = 0; ks < 43; ++ks) {
        STAGE_B((ks + 1) & 1, (ks + 1) * 32);
        KCOMP_B(ks & 1, "2");
    }
    KCOMP_B(1, "0");
#undef STAGE_B
#undef KCOMP_B

#pragma unroll
    for (int i = 0; i < 4; ++i) {
        int rowb = pr0 + wm + 16 * i + ((lane >> 4) << 2);
#pragma unroll
        for (int r = 0; r < 4; ++r) {
            int prow = rowb + r;
            if (prow - base < cnt) {
#pragma unroll
                for (int j = 0; j < 2; ++j) {
                    int col = n0 + wn + 16 * j + (lane & 15);
                    outP[(size_t)prow * DH + col] = (unsigned short)f2bf(acc[i][j][r]);
                }
            }
        }
    }
}

// ---------------- combine: out[t] = w0*outP[s0] + w1*outP[s1] (bf16 in, fp32 out) ----------------
__global__ __launch_bounds__(256) void combine_kernel(const unsigned short* __restrict__ outP,
        const int* __restrict__ tokSlot, const float* __restrict__ tokW,
        float* __restrict__ out) {
    int t = blockIdx.x;
    int c = threadIdx.x * 4;
    int s0 = tokSlot[2 * t], s1 = tokSlot[2 * t + 1];
    float w0 = tokW[2 * t], w1 = tokW[2 * t + 1];
    ushort4 a = *(const ushort4*)(outP + (size_t)s0 * DH + c);
    ushort4 b = *(const ushort4*)(outP + (size_t)s1 * DH + c);
    float4 o;
    o.x = w0 * bf2f(a.x) + w1 * bf2f(b.x);
    o.y = w0 * bf2f(a.y) + w1 * bf2f(b.y);
    o.z = w0 * bf2f(a.z) + w1 * bf2f(b.z);
    o.w = w0 * bf2f(a.w) + w1 * bf2f(b.w);
    *(float4*)(out + (size_t)t * DH + c) = o;
}

extern "C" void kernel_launch(void* const* d_in, const int* in_sizes, int n_in,
                              void* d_out, int out_size, void* d_ws, size_t ws_size,
                              hipStream_t stream) {
    const float* x  = (const float*)d_in[0];
    const float* gw = (const float*)d_in[1];
    const float* gp = (const float*)d_in[2];
    const float* up = (const float*)d_in[3];
    const float* dp = (const float*)d_in[4];
    float* out = (float*)d_out;
    float* logits = out + (size_t)T_TOK * DH;

    char* ws = (char*)d_ws;
    int*   counts    = (int*)(ws + 0);
    int*   padOff    = (int*)(ws + 128);
    int*   tokE      = (int*)(ws + 4096);                       // 32 KB
    float* tokW      = (float*)(ws + 36864);                    // 32 KB
    int*   tokSlot   = (int*)(ws + 69632);                      // 32 KB
    int*   assignTok = (int*)(ws + 102400);                     // 36 KB
    unsigned short* xb   = (unsigned short*)(ws + 147456);      // 8.39 MB
    unsigned short* gpb  = (unsigned short*)(ws + 8536064);     // 23.07 MB
    unsigned short* upb  = (unsigned short*)(ws + 31604736);    // 23.07 MB
    unsigned short* dpb  = (unsigned short*)(ws + 54673408);    // 23.07 MB
    unsigned short* h    = (unsigned short*)(ws + 77742080);    // 25.95 MB
    unsigned short* outP = (unsigned short*)(ws + 8536064);     // 18.9 MB, overlaps gpb (dead after gemmA)

    hipMemsetAsync(ws + 102400, 0, PADROWS * 4, stream);  // assignTok pad -> token 0

    const int NW4 = NE * DI * DH / 4;
    cvt3_kernel<<<dim3(1024, 3), 256, 0, stream>>>(gp, up, dp, gpb, upb, dpb, NW4);

    router_kernel<<<T_TOK / 4, 256, 0, stream>>>(x, gw, logits, tokE, tokW, xb);
    histscatter_kernel<<<1, 1024, 0, stream>>>(tokE, counts, padOff, assignTok, tokSlot);

    gemmA_kernel<<<dim3((DI / 128) * (PADROWS / 128)), 512, 0, stream>>>(xb, gpb, upb, padOff, assignTok, h);
    gemmB_kernel<<<dim3((DH / 128) * (PADROWS / 128)), 512, 0, stream>>>(h, dpb, padOff, counts, outP);
    combine_kernel<<<T_TOK, 256, 0, stream>>>(outP, tokSlot, tokW, out);
}